// Round 6
// baseline (235.208 us; speedup 1.0000x reference)
//
#include <hip/hip_runtime.h>
#include <math.h>

// ---- problem constants ----
#define NPIX 12544            // 64*14*14 pixels
#define CIN  2048
#define NB   64               // batch
#define PPIX 196              // pixels per batch image
#define BPIMG 14              // blocks per image (14 | 196)
#define PXB  14               // real pixels per block (+2 zero rows -> 16-row MFMA tile)
#define NBLK (NB * BPIMG)     // 896 blocks

typedef short  bf16x8 __attribute__((ext_vector_type(8)));
typedef short  bf16x4 __attribute__((ext_vector_type(4)));
typedef float  f32x4  __attribute__((ext_vector_type(4)));

__device__ inline unsigned short f2bf(float f) {
    // round-to-nearest-even fp32 -> bf16
    unsigned int u = __float_as_uint(f);
    u = (u + 0x7fffu + ((u >> 16) & 1u)) >> 16;
    return (unsigned short)u;
}
__device__ inline float bf2f(unsigned short u) {
    return __uint_as_float((unsigned int)u << 16);
}

// ---- kernel 0: transpose+convert W1 [2048][64] f32 -> W1t [64][2048] bf16 ----
__global__ __launch_bounds__(256) void conv_w1(
    const float* __restrict__ W1, unsigned short* __restrict__ W1t)
{
    const int id = blockIdx.x * 256 + threadIdx.x;   // 0..131071
    const int n = id >> 11;                          // out channel 0..63
    const int k = id & 2047;                         // k 0..2047
    W1t[id] = f2bf(W1[k * 64 + n]);                  // write coalesced
}

// ---- kernel 1: FUSED. One pass over x. ----
// Block = 14 real pixels of ONE image (+2 zero rows). 512 threads = 8 waves.
// Phase 1: stage x f32 -> bf16 LDS, coalesced 512B segments.
//   LDS layout xs[group g=k/8][pixel][8 bf16]: MFMA A-frag read at
//   (g*16+p)*16B is lane-linear across the wave -> conflict-free.
// Phase 2: 8-way K-split MFMA (W1t from L2, double-buffered regs);
//   h1 accumulated with LDS atomicAdd (no 34KB part buffer).
// Phase 3: MLP tail 64->16->8->1, 16 threads/pixel; a kept in LDS only.
// Phase 4: a.x weighted sum FROM LDS (bf16), shfl_xor reduce over the 16
//   pixel lanes, per-block partial to global. gap_partial is gone.
__global__ __launch_bounds__(512, 4) void fused_attn_gap(
    const float* __restrict__ x, const unsigned short* __restrict__ W1t,
    const float* __restrict__ b1,
    const float* __restrict__ W2, const float* __restrict__ b2,
    const float* __restrict__ W3, const float* __restrict__ b3,
    const float* __restrict__ W4, const float* __restrict__ b4,
    float* __restrict__ part2, float* __restrict__ asum_part)
{
    __shared__ short xs[256 * 16 * 8];   // 64 KB: [g][p][e]
    __shared__ float h1s[16][68];        // bias-init, atomicAdd accumulated
    __shared__ float h2s[16][16];
    __shared__ float h3s[16][8];
    __shared__ float a_s[16];

    const int t    = threadIdx.x;        // 0..511
    const int wv   = t >> 6;             // wave 0..7 -> K-slice
    const int lane = t & 63;
    const int l15  = lane & 15;
    const int q    = lane >> 4;
    const int blk  = blockIdx.x;
    const size_t pix0 = (size_t)blk * PXB;

    // ---- phase 1: stage x (coalesced) + init h1s with bias ----
    const int tp = t >> 5;               // pixel slot 0..15 (2 per wave)
    const int tc = t & 31;               // 32 threads per pixel
    float4 xv[16];
    if (tp < PXB) {
        const float* xp = x + (pix0 + tp) * (size_t)CIN + tc * 4;
#pragma unroll
        for (int i = 0; i < 16; ++i)
            xv[i] = *(const float4*)(xp + i * 128);  // lanes contiguous: 512B/seg
    } else {
#pragma unroll
        for (int i = 0; i < 16; ++i) xv[i] = make_float4(0.f, 0.f, 0.f, 0.f);
    }
    if (t < 256)   // h1s[p][c] = b1[c]
        *(f32x4*)&h1s[t >> 4][(t & 15) * 4] = *(const f32x4*)(b1 + (t & 15) * 4);
#pragma unroll
    for (int i = 0; i < 16; ++i) {
        const int k = tc * 4 + i * 128;   // this thread's 4 channels
        const int g = k >> 3;
        const int e = k & 7;              // 0 or 4
        bf16x4 w;
        w[0] = (short)f2bf(xv[i].x); w[1] = (short)f2bf(xv[i].y);
        w[2] = (short)f2bf(xv[i].z); w[3] = (short)f2bf(xv[i].w);
        *(bf16x4*)&xs[(g * 16 + tp) * 8 + e] = w;     // 8B, aligned
    }
    __syncthreads();

    // ---- phase 2: MFMA over this wave's K-slice [wv*256, wv*256+256) ----
    const unsigned short* wr = W1t + (size_t)l15 * CIN + wv * 256 + q * 8;
    const bf16x8* xsv = (const bf16x8*)xs;           // [g*16 + p]
    const int gq = wv * 32 + q;                      // group for step i: gq + i*4

    f32x4 acc[4] = {{0,0,0,0},{0,0,0,0},{0,0,0,0},{0,0,0,0}};
    bf16x8 wA[4], wB[4];
#pragma unroll
    for (int ct = 0; ct < 4; ++ct)
        wA[ct] = *(const bf16x8*)(wr + (size_t)ct * 16 * CIN);
#pragma unroll
    for (int i = 0; i < 8; ++i) {
        if (i < 7) {
            if ((i & 1) == 0) {
#pragma unroll
                for (int ct = 0; ct < 4; ++ct)
                    wB[ct] = *(const bf16x8*)(wr + (size_t)ct * 16 * CIN + 32 * (i + 1));
            } else {
#pragma unroll
                for (int ct = 0; ct < 4; ++ct)
                    wA[ct] = *(const bf16x8*)(wr + (size_t)ct * 16 * CIN + 32 * (i + 1));
            }
        }
        const bf16x8 av = xsv[(gq + i * 4) * 16 + l15];   // conflict-free
        if ((i & 1) == 0) {
#pragma unroll
            for (int ct = 0; ct < 4; ++ct)
                acc[ct] = __builtin_amdgcn_mfma_f32_16x16x32_bf16(av, wA[ct], acc[ct], 0, 0, 0);
        } else {
#pragma unroll
            for (int ct = 0; ct < 4; ++ct)
                acc[ct] = __builtin_amdgcn_mfma_f32_16x16x32_bf16(av, wB[ct], acc[ct], 0, 0, 0);
        }
    }
    // C/D: col = l15 (channel-in-tile), row = q*4 + r (pixel). Accumulate K-split.
#pragma unroll
    for (int ct = 0; ct < 4; ++ct)
#pragma unroll
        for (int r = 0; r < 4; ++r)
            atomicAdd(&h1s[q * 4 + r][ct * 16 + l15], acc[ct][r]);
    __syncthreads();

    // ---- phase 3: MLP tail (relu applied at h1 read) ----
    const int p = t >> 4;                // pixel (t<256)
    const int j = t & 15;
    if (t < 256) {
        float s = b2[j];
#pragma unroll
        for (int k = 0; k < 64; ++k)
            s = fmaf(fmaxf(h1s[p][k], 0.f), W2[k * 16 + j], s);
        h2s[p][j] = fmaxf(s, 0.f);
    }
    __syncthreads();
    if (t < 256 && j < 8) {
        float s = b3[j];
#pragma unroll
        for (int k = 0; k < 16; ++k) s = fmaf(h2s[p][k], W3[k * 8 + j], s);
        h3s[p][j] = fmaxf(s, 0.f);
    }
    __syncthreads();
    if (t < 256 && j == 0) {
        float z = b4[0];
#pragma unroll
        for (int k = 0; k < 8; ++k) z = fmaf(h3s[p][k], W4[k], z);
        a_s[p] = (p < PXB) ? (1.f / (1.f + expf(-z))) : 0.f;   // zero rows masked
    }
    __syncthreads();

    // per-block sum of a (for the gap_mask denominator)
    if (t == 0) {
        float s = 0.f;
#pragma unroll
        for (int pp = 0; pp < PXB; ++pp) s += a_s[pp];
        asum_part[blk] = s;
    }

    // ---- phase 4: a.x partial sums from LDS ----
    // lane (q,l15): pixel l15, groups g = wv*32 + q*8 + gi. Reduce over the
    // 16 pixel lanes with shfl_xor(width 16); lane l15==0 stores 8 channels.
    const float ap = a_s[l15];           // 0 for l15 >= 14 (zero rows are finite)
#pragma unroll
    for (int gi = 0; gi < 8; ++gi) {
        const int g = wv * 32 + q * 8 + gi;
        const bf16x8 v = xsv[g * 16 + l15];
        float sarr[8];
#pragma unroll
        for (int e = 0; e < 8; ++e)
            sarr[e] = ap * bf2f((unsigned short)v[e]);
#pragma unroll
        for (int m = 1; m < 16; m <<= 1)
#pragma unroll
            for (int e = 0; e < 8; ++e)
                sarr[e] += __shfl_xor(sarr[e], m, 16);
        if (l15 == 0) {
            float* dst = part2 + (size_t)blk * CIN + g * 8;
            *(float4*)dst       = make_float4(sarr[0], sarr[1], sarr[2], sarr[3]);
            *(float4*)(dst + 4) = make_float4(sarr[4], sarr[5], sarr[6], sarr[7]);
        }
    }
}

// ---- kernel 2: finalize. grid 64 (one per image), block 512. ----
__global__ __launch_bounds__(512) void gap_final(
    const float* __restrict__ asum_part, const float* __restrict__ part2,
    float* __restrict__ out)
{
    __shared__ float red[16];
    const int b = blockIdx.x, t = threadIdx.x;
    if (t < 16) red[t] = (t < BPIMG) ? asum_part[b * BPIMG + t] : 0.f;
    __syncthreads();
    float s = 0.f;
#pragma unroll
    for (int z = 0; z < BPIMG; ++z) s += red[z];
    const float inv = 1.f / s;

    const int c0 = t * 4;
    float4 acc = {0.f, 0.f, 0.f, 0.f};
#pragma unroll
    for (int z = 0; z < BPIMG; ++z) {
        const float4 pv = *(const float4*)(part2 + (size_t)(b * BPIMG + z) * CIN + c0);
        acc.x += pv.x; acc.y += pv.y; acc.z += pv.z; acc.w += pv.w;
    }
    float4 r;
    r.x = acc.x * inv; r.y = acc.y * inv; r.z = acc.z * inv; r.w = acc.w * inv;
    *(float4*)(out + (size_t)b * CIN + c0) = r;
}

extern "C" void kernel_launch(void* const* d_in, const int* in_sizes, int n_in,
                              void* d_out, int out_size, void* d_ws, size_t ws_size,
                              hipStream_t stream)
{
    const float* x  = (const float*)d_in[0];
    const float* W1 = (const float*)d_in[1];
    const float* b1 = (const float*)d_in[2];
    const float* W2 = (const float*)d_in[3];
    const float* b2 = (const float*)d_in[4];
    const float* W3 = (const float*)d_in[5];
    const float* b3 = (const float*)d_in[6];
    const float* W4 = (const float*)d_in[7];
    const float* b4 = (const float*)d_in[8];
    float* out = (float*)d_out;

    // ws layout: W1t bf16 [64][2048] @0 (256KB) | asum_part f32 [896] @512KB |
    //            part2 f32 [896][2048] @1MB (7.34MB). Total ~8.4 MB.
    unsigned short* W1t = (unsigned short*)d_ws;
    float* asum_part = (float*)((char*)d_ws + (512 << 10));
    float* part2     = (float*)((char*)d_ws + (1 << 20));

    conv_w1<<<512, 256, 0, stream>>>(W1, W1t);
    fused_attn_gap<<<NBLK, 512, 0, stream>>>(x, W1t, b1, W2, b2, W3, b3, W4, b4,
                                             part2, asum_part);
    gap_final<<<NB, 512, 0, stream>>>(asum_part, part2, out);
}